// Round 3
// baseline (1699.578 us; speedup 1.0000x reference)
//
#include <hip/hip_runtime.h>
#include <hip/hip_bf16.h>
#include <stdint.h>

#define AS1 __attribute__((address_space(1)))
#define AS3 __attribute__((address_space(3)))

typedef unsigned short ushort_t;
typedef __attribute__((ext_vector_type(8))) short short8;
typedef __attribute__((ext_vector_type(4))) float floatx4;

// ---------- helpers ----------
__device__ __forceinline__ ushort_t f2b(float f) {
    union { float f; unsigned int i; } x; x.f = f;
    unsigned int r = x.i + 0x7fffu + ((x.i >> 16) & 1u);   // RNE
    return (ushort_t)(r >> 16);
}
// async global->LDS, 16B per lane. LDS dest must be wave-uniform base + lane*16.
__device__ __forceinline__ void gl2lds16(const void* g, void* l) {
    __builtin_amdgcn_global_load_lds(
        (const AS1 unsigned int*)g,
        (AS3 unsigned int*)l,
        16, 0, 0);
}

static constexpr int CCH = 512;
static constexpr int NSP = 4096;   // 64*64 spatial
static constexpr int NG  = 32;
static constexpr int RCH = 1024;   // attention row-chunk

// ---------- kernel 1: GroupNorm stats (one block per (b,g); group = 65536 contiguous fp32) ----
__global__ __launch_bounds__(256) void gn_stats(const float* __restrict__ x,
                                                float* __restrict__ mean,
                                                float* __restrict__ rstd) {
    const long base = (long)blockIdx.x * 65536;
    const int t = threadIdx.x;
    float s1 = 0.f, s2 = 0.f;
    for (int i = t * 8; i < 65536; i += 256 * 8) {
        float4 a = *(const float4*)(x + base + i);
        float4 b = *(const float4*)(x + base + i + 4);
        s1 += a.x + a.y + a.z + a.w + b.x + b.y + b.z + b.w;
        s2 += a.x * a.x + a.y * a.y + a.z * a.z + a.w * a.w
            + b.x * b.x + b.y * b.y + b.z * b.z + b.w * b.w;
    }
#pragma unroll
    for (int o = 32; o; o >>= 1) { s1 += __shfl_xor(s1, o, 64); s2 += __shfl_xor(s2, o, 64); }
    __shared__ float r1[4], r2[4];
    const int lane = t & 63, wave = t >> 6;
    if (!lane) { r1[wave] = s1; r2[wave] = s2; }
    __syncthreads();
    if (!t) {
        float S1 = r1[0] + r1[1] + r1[2] + r1[3];
        float S2 = r2[0] + r2[1] + r2[2] + r2[3];
        float mu = S1 * (1.f / 65536.f);
        float var = S2 * (1.f / 65536.f) - mu * mu;
        mean[blockIdx.x] = mu;
        rstd[blockIdx.x] = rsqrtf(var + 1e-5f);
    }
}

// ---------- kernel 2: fp32 weights -> bf16 (4 matrices of 512x512) ----------
__global__ __launch_bounds__(256) void w_to_bf16(const float* __restrict__ q,
                                                 const float* __restrict__ k,
                                                 const float* __restrict__ v,
                                                 const float* __restrict__ p,
                                                 ushort_t* __restrict__ out) {
    const float* srcs[4] = { q, k, v, p };
    const float* s = srcs[blockIdx.y];
    const long i = ((long)blockIdx.x * 256 + threadIdx.x) * 4;
    float4 f = *(const float4*)(s + i);
    ushort_t o[4] __attribute__((aligned(8)));
    o[0] = f2b(f.x); o[1] = f2b(f.y); o[2] = f2b(f.z); o[3] = f2b(f.w);
    *(ushort4*)(out + (long)blockIdx.y * 262144 + i) = *(ushort4*)o;
}

// ---------- kernel 3: normalize + transpose: ht[b][n][c] = bf16(gn(x)[b][c][n]) ----------
__global__ __launch_bounds__(256) void norm_transpose(const float* __restrict__ x,
                                                      const float* __restrict__ gw,
                                                      const float* __restrict__ gb,
                                                      const float* __restrict__ mean,
                                                      const float* __restrict__ rstd,
                                                      ushort_t* __restrict__ ht) {
    __shared__ ushort_t tile[64 * 65];   // [c][n], pad 65 to spread banks
    const int b = blockIdx.z, c0 = blockIdx.y * 64, n0 = blockIdx.x * 64;
    const int t = threadIdx.x;
    const float* xb = x + ((long)b * CCH + c0) * NSP + n0;
#pragma unroll
    for (int p = 0; p < 2; ++p) {
        int li = p * 2048 + t * 8;
        int cl = li >> 6, nl = li & 63;
        int c = c0 + cl, g = c >> 4;
        float mu = mean[b * NG + g], rs = rstd[b * NG + g];
        float w  = gw[c] * rs;
        float bb = gb[c] - mu * w;
        float4 a = *(const float4*)(xb + (long)cl * NSP + nl);
        float4 d = *(const float4*)(xb + (long)cl * NSP + nl + 4);
        float f[8] = { a.x, a.y, a.z, a.w, d.x, d.y, d.z, d.w };
#pragma unroll
        for (int j = 0; j < 8; ++j) tile[cl * 65 + nl + j] = f2b(f[j] * w + bb);
    }
    __syncthreads();
#pragma unroll
    for (int p = 0; p < 2; ++p) {
        int li = p * 2048 + t * 8;
        int nl = li >> 6, cl = li & 63;
        ushort_t v[8] __attribute__((aligned(16)));
#pragma unroll
        for (int j = 0; j < 8; ++j) v[j] = tile[(cl + j) * 65 + nl];
        *(uint4*)(ht + ((long)b * NSP + n0 + nl) * CCH + c0 + cl) = *(uint4*)v;
    }
}

// ---------- the one GEMM: C[m][n] = scale * sum_k A[m][k]*B[n][k] (+bias)(+resid) ----------
// A,B bf16. BIAS: 0 none, 1 per-m, 2 per-n (fp32). OUTF32: fp32 C (else bf16). RES: add fp32 residual.
template <int BIAS, int OUTF32, int RES>
__global__ __launch_bounds__(256, 2) void gemm_tn(
    const ushort_t* __restrict__ A, int lda, long sA,
    const ushort_t* __restrict__ B, int ldb, long sB,
    void* __restrict__ Cp, int ldc, long sC,
    const float* __restrict__ bias,
    const float* __restrict__ resid, long sR,
    float scale, int K) {
    __shared__ short As[128 * 32];
    __shared__ short Bs[128 * 32];
    const int t = threadIdx.x;
    const int lane = t & 63, wave = t >> 6;
    const long bz = blockIdx.z;
    const int m0 = blockIdx.y * 128, n0 = blockIdx.x * 128;

    const ushort_t* Ab = A + bz * sA + (long)(m0 + (t >> 2)) * lda + (t & 3) * 8;
    const ushort_t* Bb = B + bz * sB + (long)(n0 + (t >> 2)) * ldb + (t & 3) * 8;
    short* la = As + t * 8;
    short* lb = Bs + t * 8;

    const int wm = (wave & 1) * 64, wn = (wave >> 1) * 64;
    const int lm = lane & 15, lk = (lane >> 4) * 8;
    const short* pa = As + (wm + lm) * 32 + lk;
    const short* pb = Bs + (wn + lm) * 32 + lk;

    floatx4 acc[4][4];
#pragma unroll
    for (int i = 0; i < 4; ++i)
#pragma unroll
        for (int j = 0; j < 4; ++j) acc[i][j] = (floatx4){0.f, 0.f, 0.f, 0.f};

    for (int k0 = 0; k0 < K; k0 += 32) {
        __syncthreads();
        gl2lds16(Ab, la);
        gl2lds16(Ab + 64 * (long)lda, la + 64 * 32);
        gl2lds16(Bb, lb);
        gl2lds16(Bb + 64 * (long)ldb, lb + 64 * 32);
        Ab += 32; Bb += 32;
        __builtin_amdgcn_s_waitcnt(0);
        __syncthreads();
        short8 af[4], bfr[4];
#pragma unroll
        for (int i = 0; i < 4; ++i) af[i]  = *(const short8*)(pa + i * 16 * 32);
#pragma unroll
        for (int i = 0; i < 4; ++i) bfr[i] = *(const short8*)(pb + i * 16 * 32);
#pragma unroll
        for (int mi = 0; mi < 4; ++mi)
#pragma unroll
            for (int ni = 0; ni < 4; ++ni)
                acc[mi][ni] = __builtin_amdgcn_mfma_f32_16x16x32_bf16(af[mi], bfr[ni], acc[mi][ni], 0, 0, 0);
    }

    // epilogue: C/D layout col=lane&15, row=(lane>>4)*4+reg
    const int row4 = (lane >> 4) * 4;
    const int ncol = lane & 15;
#pragma unroll
    for (int mi = 0; mi < 4; ++mi) {
#pragma unroll
        for (int ni = 0; ni < 4; ++ni) {
            const int n = n0 + wn + ni * 16 + ncol;
            float bn = (BIAS == 2) ? bias[n] : 0.f;
#pragma unroll
            for (int r = 0; r < 4; ++r) {
                const int m = m0 + wm + mi * 16 + row4 + r;
                float v = acc[mi][ni][r] * scale;
                if (BIAS == 1) v += bias[m];
                if (BIAS == 2) v += bn;
                if (RES) v += resid[bz * sR + (long)m * ldc + n];
                const long idx = bz * sC + (long)m * ldc + n;
                if (OUTF32) ((float*)Cp)[idx] = v;
                else        ((ushort_t*)Cp)[idx] = f2b(v);
            }
        }
    }
}

// ---------- softmax over rows of S (fp32 [rows][4096]) -> P (bf16) ----------
__global__ __launch_bounds__(256) void softmax_rows(const float* __restrict__ S,
                                                    ushort_t* __restrict__ P) {
    const long row = blockIdx.x;
    const float* s = S + row * 4096;
    ushort_t* p = P + row * 4096;
    const int t = threadIdx.x;
    float v[16];
    float mx = -3.4e38f;
#pragma unroll
    for (int c = 0; c < 4; ++c) {
        float4 q = *(const float4*)(s + c * 1024 + t * 4);
        v[c * 4 + 0] = q.x; v[c * 4 + 1] = q.y; v[c * 4 + 2] = q.z; v[c * 4 + 3] = q.w;
        mx = fmaxf(mx, fmaxf(fmaxf(q.x, q.y), fmaxf(q.z, q.w)));
    }
#pragma unroll
    for (int o = 32; o; o >>= 1) mx = fmaxf(mx, __shfl_xor(mx, o, 64));
    __shared__ float rA[4], rB[4];
    const int lane = t & 63, wave = t >> 6;
    if (!lane) rA[wave] = mx;
    __syncthreads();
    mx = fmaxf(fmaxf(rA[0], rA[1]), fmaxf(rA[2], rA[3]));
    float sum = 0.f;
#pragma unroll
    for (int i = 0; i < 16; ++i) { v[i] = __expf(v[i] - mx); sum += v[i]; }
#pragma unroll
    for (int o = 32; o; o >>= 1) sum += __shfl_xor(sum, o, 64);
    if (!lane) rB[wave] = sum;
    __syncthreads();
    sum = rB[0] + rB[1] + rB[2] + rB[3];
    const float inv = 1.f / sum;
#pragma unroll
    for (int c = 0; c < 4; ++c) {
        ushort_t o8[4] __attribute__((aligned(8)));
#pragma unroll
        for (int j = 0; j < 4; ++j) o8[j] = f2b(v[c * 4 + j] * inv);
        *(ushort4*)(p + c * 1024 + t * 4) = *(ushort4*)o8;
    }
}

// ---------- host ----------
extern "C" void kernel_launch(void* const* d_in, const int* in_sizes, int n_in,
                              void* d_out, int out_size, void* d_ws, size_t ws_size,
                              hipStream_t stream) {
    const float* x   = (const float*)d_in[0];
    const float* gnw = (const float*)d_in[1];
    const float* gnb = (const float*)d_in[2];
    const float* qw  = (const float*)d_in[3];
    const float* qb  = (const float*)d_in[4];
    const float* kw  = (const float*)d_in[5];
    const float* kb  = (const float*)d_in[6];
    const float* vw  = (const float*)d_in[7];
    const float* vb  = (const float*)d_in[8];
    const float* pw  = (const float*)d_in[9];
    const float* pb  = (const float*)d_in[10];
    float* out = (float*)d_out;
    (void)in_sizes; (void)n_in; (void)out_size; (void)ws_size;

    const long E = (long)NSP * CCH;          // 2,097,152 elems per batch matrix
    // workspace layout (~94 MB total)
    char* ws = (char*)d_ws;
    float*    mean = (float*)ws;               // 128 f32
    float*    rstd = (float*)(ws + 512);       // 128 f32
    ushort_t* wb   = (ushort_t*)(ws + 1024);   // [4][512*512] bf16 weights (2 MB)
    ushort_t* ht   = wb + 4 * 262144;          // [4][4096][512] bf16 (16.78 MB)
    ushort_t* Kt   = ht + 4 * E;               // [4][4096][512]
    ushort_t* V    = Kt + 4 * E;               // [4][512][4096]
    ushort_t* Qt   = V  + 4 * E;               // [4][4096][512]; hOT aliases (Q rows die after use)
    ushort_t* hOT  = Qt;
    ushort_t* Pc   = Qt + 4 * E;               // [1024][4096] bf16 chunk (8.39 MB)
    float*    Sc   = (float*)(Pc + (long)RCH * NSP);  // [1024][4096] f32 chunk (16.78 MB)
    ushort_t* qwb = wb, *kwb = wb + 262144, *vwb = wb + 2 * 262144, *pwb = wb + 3 * 262144;

    // 1) GroupNorm stats + weight conversion
    gn_stats<<<128, 256, 0, stream>>>(x, mean, rstd);
    w_to_bf16<<<dim3(256, 4), 256, 0, stream>>>(qw, kw, vw, pw, wb);
    // 2) normalize + transpose
    norm_transpose<<<dim3(64, 8, 4), 256, 0, stream>>>(x, gnw, gnb, mean, rstd, ht);
    // 3) QKV projections
    //    Qt[n][o] = sum_c ht[n][c]*qw[o][c] + qb[o]   (bias per-n')
    gemm_tn<2, 0, 0><<<dim3(4, 32, 4), 256, 0, stream>>>(ht, 512, E, qwb, 512, 0, Qt, 512, E, qb, nullptr, 0, 1.f, 512);
    gemm_tn<2, 0, 0><<<dim3(4, 32, 4), 256, 0, stream>>>(ht, 512, E, kwb, 512, 0, Kt, 512, E, kb, nullptr, 0, 1.f, 512);
    //    V[o][n] = sum_c vw[o][c]*ht[n][c] + vb[o]    (bias per-m)
    gemm_tn<1, 0, 0><<<dim3(32, 4, 4), 256, 0, stream>>>(vwb, 512, 0, ht, 512, E, V, 4096, E, vb, nullptr, 0, 1.f, 512);
    // 4) per (batch, row-chunk): scores (fp32) -> softmax -> P chunk -> PV chunk
    const float scl = 0.044194173824159216f;  // 512^-0.5
    for (int b = 0; b < 4; ++b) {
        for (int r = 0; r < NSP / RCH; ++r) {
            const ushort_t* Qrow = Qt + b * E + (long)r * RCH * CCH;
            // Sc[i][j] = scl * Q[r*RCH+i] . K[j]
            gemm_tn<0, 1, 0><<<dim3(32, RCH / 128, 1), 256, 0, stream>>>(
                Qrow, 512, 0, Kt + b * E, 512, 0, Sc, 4096, 0, nullptr, nullptr, 0, scl, 512);
            softmax_rows<<<RCH, 256, 0, stream>>>(Sc, Pc);
            // hOT[r*RCH+i][c] = sum_j Pc[i][j] * V[c][j]   (overwrites consumed Q rows)
            gemm_tn<0, 0, 0><<<dim3(4, RCH / 128, 1), 256, 0, stream>>>(
                Pc, 4096, 0, V + b * E, 4096, 0,
                hOT + b * E + (long)r * RCH * CCH, 512, 0, nullptr, nullptr, 0, 1.f, 4096);
        }
    }
    // 6) out = x + pw @ h_out + pb   (fp32 out, fp32 residual)
    gemm_tn<1, 1, 1><<<dim3(32, 4, 4), 256, 0, stream>>>(pwb, 512, 0, hOT, 512, E,
                                                         out, 4096, E, pb, x, E, 1.f, 512);
}

// Round 4
// 635.503 us; speedup vs baseline: 2.6744x; 2.6744x over previous
//
#include <hip/hip_runtime.h>
#include <hip/hip_bf16.h>
#include <stdint.h>

#define AS1 __attribute__((address_space(1)))
#define AS3 __attribute__((address_space(3)))

typedef unsigned short ushort_t;
typedef __attribute__((ext_vector_type(8))) short short8;
typedef __attribute__((ext_vector_type(4))) float floatx4;

// ---------- helpers ----------
__device__ __forceinline__ ushort_t f2b(float f) {
    union { float f; unsigned int i; } x; x.f = f;
    unsigned int r = x.i + 0x7fffu + ((x.i >> 16) & 1u);   // RNE
    return (ushort_t)(r >> 16);
}
// async global->LDS, 16B per lane. LDS dest must be wave-uniform base + lane*16.
__device__ __forceinline__ void gl2lds16(const void* g, void* l) {
    __builtin_amdgcn_global_load_lds(
        (const AS1 unsigned int*)g,
        (AS3 unsigned int*)l,
        16, 0, 0);
}

static constexpr int CCH = 512;
static constexpr int NSP = 4096;   // 64*64 spatial
static constexpr int NG  = 32;
static constexpr int RCH = 2048;   // attention row-chunk (half a batch)
static constexpr int NSLC = 8;     // PV split-K slices (K=4096 -> 8 x 512)

// ---------- kernel 1: GroupNorm stats (one block per (b,g); group = 65536 contiguous fp32) ----
__global__ __launch_bounds__(256) void gn_stats(const float* __restrict__ x,
                                                float* __restrict__ mean,
                                                float* __restrict__ rstd) {
    const long base = (long)blockIdx.x * 65536;
    const int t = threadIdx.x;
    float s1 = 0.f, s2 = 0.f;
    for (int i = t * 8; i < 65536; i += 256 * 8) {
        float4 a = *(const float4*)(x + base + i);
        float4 b = *(const float4*)(x + base + i + 4);
        s1 += a.x + a.y + a.z + a.w + b.x + b.y + b.z + b.w;
        s2 += a.x * a.x + a.y * a.y + a.z * a.z + a.w * a.w
            + b.x * b.x + b.y * b.y + b.z * b.z + b.w * b.w;
    }
#pragma unroll
    for (int o = 32; o; o >>= 1) { s1 += __shfl_xor(s1, o, 64); s2 += __shfl_xor(s2, o, 64); }
    __shared__ float r1[4], r2[4];
    const int lane = t & 63, wave = t >> 6;
    if (!lane) { r1[wave] = s1; r2[wave] = s2; }
    __syncthreads();
    if (!t) {
        float S1 = r1[0] + r1[1] + r1[2] + r1[3];
        float S2 = r2[0] + r2[1] + r2[2] + r2[3];
        float mu = S1 * (1.f / 65536.f);
        float var = S2 * (1.f / 65536.f) - mu * mu;
        mean[blockIdx.x] = mu;
        rstd[blockIdx.x] = rsqrtf(var + 1e-5f);
    }
}

// ---------- kernel 2: fp32 weights -> bf16 (4 matrices of 512x512) ----------
__global__ __launch_bounds__(256) void w_to_bf16(const float* __restrict__ q,
                                                 const float* __restrict__ k,
                                                 const float* __restrict__ v,
                                                 const float* __restrict__ p,
                                                 ushort_t* __restrict__ out) {
    const float* srcs[4] = { q, k, v, p };
    const float* s = srcs[blockIdx.y];
    const long i = ((long)blockIdx.x * 256 + threadIdx.x) * 4;
    float4 f = *(const float4*)(s + i);
    ushort_t o[4] __attribute__((aligned(8)));
    o[0] = f2b(f.x); o[1] = f2b(f.y); o[2] = f2b(f.z); o[3] = f2b(f.w);
    *(ushort4*)(out + (long)blockIdx.y * 262144 + i) = *(ushort4*)o;
}

// ---------- kernel 3: normalize + transpose: ht[b][n][c] = bf16(gn(x)[b][c][n]) ----------
__global__ __launch_bounds__(256) void norm_transpose(const float* __restrict__ x,
                                                      const float* __restrict__ gw,
                                                      const float* __restrict__ gb,
                                                      const float* __restrict__ mean,
                                                      const float* __restrict__ rstd,
                                                      ushort_t* __restrict__ ht) {
    __shared__ ushort_t tile[64 * 65];   // [c][n], pad 65 to spread banks
    const int b = blockIdx.z, c0 = blockIdx.y * 64, n0 = blockIdx.x * 64;
    const int t = threadIdx.x;
    const float* xb = x + ((long)b * CCH + c0) * NSP + n0;
#pragma unroll
    for (int p = 0; p < 2; ++p) {
        int li = p * 2048 + t * 8;
        int cl = li >> 6, nl = li & 63;
        int c = c0 + cl, g = c >> 4;
        float mu = mean[b * NG + g], rs = rstd[b * NG + g];
        float w  = gw[c] * rs;
        float bb = gb[c] - mu * w;
        float4 a = *(const float4*)(xb + (long)cl * NSP + nl);
        float4 d = *(const float4*)(xb + (long)cl * NSP + nl + 4);
        float f[8] = { a.x, a.y, a.z, a.w, d.x, d.y, d.z, d.w };
#pragma unroll
        for (int j = 0; j < 8; ++j) tile[cl * 65 + nl + j] = f2b(f[j] * w + bb);
    }
    __syncthreads();
#pragma unroll
    for (int p = 0; p < 2; ++p) {
        int li = p * 2048 + t * 8;
        int nl = li >> 6, cl = li & 63;
        ushort_t v[8] __attribute__((aligned(16)));
#pragma unroll
        for (int j = 0; j < 8; ++j) v[j] = tile[(cl + j) * 65 + nl];
        *(uint4*)(ht + ((long)b * NSP + n0 + nl) * CCH + c0 + cl) = *(uint4*)v;
    }
}

// ---------- the one GEMM: C[m][n] = scale * sum_k A[m][k]*B[n][k] (+bias)(+resid) ----------
// A,B bf16. BIAS: 0 none, 1 per-m, 2 per-n (fp32). OUTF32: fp32 C (else bf16). RES: add fp32 residual.
template <int BIAS, int OUTF32, int RES>
__global__ __launch_bounds__(256, 2) void gemm_tn(
    const ushort_t* __restrict__ A, int lda, long sA,
    const ushort_t* __restrict__ B, int ldb, long sB,
    void* __restrict__ Cp, int ldc, long sC,
    const float* __restrict__ bias,
    const float* __restrict__ resid, long sR,
    float scale, int K) {
    __shared__ short As[128 * 32];
    __shared__ short Bs[128 * 32];
    const int t = threadIdx.x;
    const int lane = t & 63, wave = t >> 6;
    const long bz = blockIdx.z;
    const int m0 = blockIdx.y * 128, n0 = blockIdx.x * 128;

    const ushort_t* Ab = A + bz * sA + (long)(m0 + (t >> 2)) * lda + (t & 3) * 8;
    const ushort_t* Bb = B + bz * sB + (long)(n0 + (t >> 2)) * ldb + (t & 3) * 8;
    short* la = As + t * 8;
    short* lb = Bs + t * 8;

    const int wm = (wave & 1) * 64, wn = (wave >> 1) * 64;
    const int lm = lane & 15, lk = (lane >> 4) * 8;
    const short* pa = As + (wm + lm) * 32 + lk;
    const short* pb = Bs + (wn + lm) * 32 + lk;

    floatx4 acc[4][4];
#pragma unroll
    for (int i = 0; i < 4; ++i)
#pragma unroll
        for (int j = 0; j < 4; ++j) acc[i][j] = (floatx4){0.f, 0.f, 0.f, 0.f};

    for (int k0 = 0; k0 < K; k0 += 32) {
        __syncthreads();
        gl2lds16(Ab, la);
        gl2lds16(Ab + 64 * (long)lda, la + 64 * 32);
        gl2lds16(Bb, lb);
        gl2lds16(Bb + 64 * (long)ldb, lb + 64 * 32);
        Ab += 32; Bb += 32;
        __builtin_amdgcn_s_waitcnt(0);
        __syncthreads();
        short8 af[4], bfr[4];
#pragma unroll
        for (int i = 0; i < 4; ++i) af[i]  = *(const short8*)(pa + i * 16 * 32);
#pragma unroll
        for (int i = 0; i < 4; ++i) bfr[i] = *(const short8*)(pb + i * 16 * 32);
#pragma unroll
        for (int mi = 0; mi < 4; ++mi)
#pragma unroll
            for (int ni = 0; ni < 4; ++ni)
                acc[mi][ni] = __builtin_amdgcn_mfma_f32_16x16x32_bf16(af[mi], bfr[ni], acc[mi][ni], 0, 0, 0);
    }

    // epilogue: C/D layout col=lane&15, row=(lane>>4)*4+reg
    const int row4 = (lane >> 4) * 4;
    const int ncol = lane & 15;
#pragma unroll
    for (int mi = 0; mi < 4; ++mi) {
#pragma unroll
        for (int ni = 0; ni < 4; ++ni) {
            const int n = n0 + wn + ni * 16 + ncol;
            float bn = (BIAS == 2) ? bias[n] : 0.f;
#pragma unroll
            for (int r = 0; r < 4; ++r) {
                const int m = m0 + wm + mi * 16 + row4 + r;
                float v = acc[mi][ni][r] * scale;
                if (BIAS == 1) v += bias[m];
                if (BIAS == 2) v += bn;
                if (RES) v += resid[bz * sR + (long)m * ldc + n];
                const long idx = bz * sC + (long)m * ldc + n;
                if (OUTF32) ((float*)Cp)[idx] = v;
                else        ((ushort_t*)Cp)[idx] = f2b(v);
            }
        }
    }
}

// ---------- softmax over rows of S (fp32 [rows][4096]) -> P (bf16) ----------
__global__ __launch_bounds__(256) void softmax_rows(const float* __restrict__ S,
                                                    ushort_t* __restrict__ P) {
    const long row = blockIdx.x;
    const float* s = S + row * 4096;
    ushort_t* p = P + row * 4096;
    const int t = threadIdx.x;
    float v[16];
    float mx = -3.4e38f;
#pragma unroll
    for (int c = 0; c < 4; ++c) {
        float4 q = *(const float4*)(s + c * 1024 + t * 4);
        v[c * 4 + 0] = q.x; v[c * 4 + 1] = q.y; v[c * 4 + 2] = q.z; v[c * 4 + 3] = q.w;
        mx = fmaxf(mx, fmaxf(fmaxf(q.x, q.y), fmaxf(q.z, q.w)));
    }
#pragma unroll
    for (int o = 32; o; o >>= 1) mx = fmaxf(mx, __shfl_xor(mx, o, 64));
    __shared__ float rA[4], rB[4];
    const int lane = t & 63, wave = t >> 6;
    if (!lane) rA[wave] = mx;
    __syncthreads();
    mx = fmaxf(fmaxf(rA[0], rA[1]), fmaxf(rA[2], rA[3]));
    float sum = 0.f;
#pragma unroll
    for (int i = 0; i < 16; ++i) { v[i] = __expf(v[i] - mx); sum += v[i]; }
#pragma unroll
    for (int o = 32; o; o >>= 1) sum += __shfl_xor(sum, o, 64);
    if (!lane) rB[wave] = sum;
    __syncthreads();
    sum = rB[0] + rB[1] + rB[2] + rB[3];
    const float inv = 1.f / sum;
#pragma unroll
    for (int c = 0; c < 4; ++c) {
        ushort_t o8[4] __attribute__((aligned(8)));
#pragma unroll
        for (int j = 0; j < 4; ++j) o8[j] = f2b(v[c * 4 + j] * inv);
        *(ushort4*)(p + c * 1024 + t * 4) = *(ushort4*)o8;
    }
}

// ---------- reduce split-K partials: out[m][c] = bf16(sum_s part[s][m][c]) ----------
__global__ __launch_bounds__(256) void reduce_slices(const float* __restrict__ part,
                                                     ushort_t* __restrict__ out) {
    const long i = ((long)blockIdx.x * 256 + threadIdx.x) * 4;   // over RCH*512
    float4 s = *(const float4*)(part + i);
#pragma unroll
    for (int sl = 1; sl < NSLC; ++sl) {
        float4 a = *(const float4*)(part + (long)sl * RCH * 512 + i);
        s.x += a.x; s.y += a.y; s.z += a.z; s.w += a.w;
    }
    ushort_t o[4] __attribute__((aligned(8)));
    o[0] = f2b(s.x); o[1] = f2b(s.y); o[2] = f2b(s.z); o[3] = f2b(s.w);
    *(ushort4*)(out + i) = *(ushort4*)o;
}

// ---------- host ----------
extern "C" void kernel_launch(void* const* d_in, const int* in_sizes, int n_in,
                              void* d_out, int out_size, void* d_ws, size_t ws_size,
                              hipStream_t stream) {
    const float* x   = (const float*)d_in[0];
    const float* gnw = (const float*)d_in[1];
    const float* gnb = (const float*)d_in[2];
    const float* qw  = (const float*)d_in[3];
    const float* qb  = (const float*)d_in[4];
    const float* kw  = (const float*)d_in[5];
    const float* kb  = (const float*)d_in[6];
    const float* vw  = (const float*)d_in[7];
    const float* vb  = (const float*)d_in[8];
    const float* pw  = (const float*)d_in[9];
    const float* pb  = (const float*)d_in[10];
    float* out = (float*)d_out;
    (void)in_sizes; (void)n_in; (void)out_size; (void)ws_size;

    const long E = (long)NSP * CCH;            // 2,097,152 elems per batch matrix
    // workspace layout (~103 MB; aliasing: Pc<-ht (dead after QKV), partials<-Sc (dead after softmax),
    // hOT<-Qt (Q rows consumed by their own chunk's scores GEMM before reduce writes them))
    char* ws = (char*)d_ws;
    float*    mean = (float*)ws;               // 128 f32
    float*    rstd = (float*)(ws + 512);       // 128 f32
    ushort_t* wb   = (ushort_t*)(ws + 1024);   // [4][512*512] bf16 weights (2 MB)
    ushort_t* ht   = wb + 4 * 262144;          // [4][4096][512] bf16 (16.78 MB)  | aliased by Pc
    ushort_t* Kt   = ht + 4 * E;               // [4][4096][512]
    ushort_t* V    = Kt + 4 * E;               // [4][512][4096]
    ushort_t* Qt   = V  + 4 * E;               // [4][4096][512]; hOT aliases
    ushort_t* hOT  = Qt;
    float*    Sc   = (float*)(Qt + 4 * E);     // [2048][4096] f32 chunk (33.55 MB) | aliased by partials
    ushort_t* Pc   = ht;                       // [2048][4096] bf16 chunk (16.78 MB)
    float*    part = Sc;                       // [8][2048][512] f32 split-K partials (33.55 MB)
    ushort_t* qwb = wb, *kwb = wb + 262144, *vwb = wb + 2 * 262144, *pwb = wb + 3 * 262144;

    // 1) GroupNorm stats + weight conversion
    gn_stats<<<128, 256, 0, stream>>>(x, mean, rstd);
    w_to_bf16<<<dim3(256, 4), 256, 0, stream>>>(qw, kw, vw, pw, wb);
    // 2) normalize + transpose
    norm_transpose<<<dim3(64, 8, 4), 256, 0, stream>>>(x, gnw, gnb, mean, rstd, ht);
    // 3) QKV projections
    gemm_tn<2, 0, 0><<<dim3(4, 32, 4), 256, 0, stream>>>(ht, 512, E, qwb, 512, 0, Qt, 512, E, qb, nullptr, 0, 1.f, 512);
    gemm_tn<2, 0, 0><<<dim3(4, 32, 4), 256, 0, stream>>>(ht, 512, E, kwb, 512, 0, Kt, 512, E, kb, nullptr, 0, 1.f, 512);
    gemm_tn<1, 0, 0><<<dim3(32, 4, 4), 256, 0, stream>>>(vwb, 512, 0, ht, 512, E, V, 4096, E, vb, nullptr, 0, 1.f, 512);
    // 4) per (batch, half): scores (fp32) -> softmax -> P -> split-K PV -> reduce
    const float scl = 0.044194173824159216f;  // 512^-0.5
    for (int b = 0; b < 4; ++b) {
        for (int h = 0; h < NSP / RCH; ++h) {
            const long rowOff = (long)h * RCH * CCH;
            // Sc[i][j] = scl * Q[h*RCH+i] . K[j]   grid 512 blocks
            gemm_tn<0, 1, 0><<<dim3(32, RCH / 128, 1), 256, 0, stream>>>(
                Qt + b * E + rowOff, 512, 0, Kt + b * E, 512, 0, Sc, 4096, 0, nullptr, nullptr, 0, scl, 512);
            softmax_rows<<<RCH, 256, 0, stream>>>(Sc, Pc);
            // part[s][i][c] = sum_{j in slice s} Pc[i][j] * V[c][j]   grid (4,16,8)=512 blocks
            gemm_tn<0, 1, 0><<<dim3(4, RCH / 128, NSLC), 256, 0, stream>>>(
                Pc, 4096, 512, V + b * E, 4096, 512,
                part, 512, (long)RCH * 512, nullptr, nullptr, 0, 1.f, 512);
            reduce_slices<<<RCH * 512 / 1024, 256, 0, stream>>>(part, hOT + b * E + rowOff);
        }
    }
    // 5) out = x + pw @ h_out + pb   (fp32 out, fp32 residual)
    gemm_tn<1, 1, 1><<<dim3(32, 4, 4), 256, 0, stream>>>(pwb, 512, 0, hOT, 512, E,
                                                         out, 4096, E, pb, x, E, 1.f, 512);
}